// Round 8
// baseline (180.300 us; speedup 1.0000x reference)
//
#include <hip/hip_runtime.h>

#define OUT_H 7
#define OUT_W 7
#define NBINS (OUT_H * OUT_W)           // 49
#define NSAMP (NBINS * 2 * 2)           // 196 sample points per ROI
#define CCH 256
#define FH 256
#define FW 256
#define HW (FH * FW)
#define CHW (CCH * HW)
#define SCALE 0.25f

typedef float v4f __attribute__((ext_vector_type(4)));

// ---------- bf16 helpers (RNE) ----------
__device__ __forceinline__ unsigned int f2bf(float f) {
    unsigned int u = __float_as_uint(f);
    u += 0x7FFFu + ((u >> 16) & 1u);
    return u >> 16;
}
#define BFLO(u) __uint_as_float((u) << 16)
#define BFHI(u) __uint_as_float((u) & 0xFFFF0000u)

// ==================================================================
// Phase 1: transpose BCHW fp32 -> BHWC bf16 (featT in d_ws).
// Tile 64 channels x 64 spatial. float4 reads, uint4 bf16-packed writes.
// Plain stores: featT SHOULD allocate in L3 (gather reads it 3x).
// (unchanged from round 7)
// ==================================================================
__global__ __launch_bounds__(256) void transpose_kernel(
    const float* __restrict__ feat, unsigned int* __restrict__ featT)
{
    __shared__ float tile[64][65];
    const int t  = threadIdx.x;
    const int s0 = blockIdx.x * 64;
    const int c0 = blockIdx.y * 64;
    const int b  = blockIdx.z;

    const float* inb = feat + (size_t)b * CHW + (size_t)c0 * HW + s0;

    const int rx = (t & 15) * 4;
    const int rc = t >> 4;
    #pragma unroll
    for (int pass = 0; pass < 4; ++pass) {
        int c = pass * 16 + rc;
        float4 v = *(const float4*)(inb + (size_t)c * HW + rx);
        tile[c][rx]     = v.x;
        tile[c][rx + 1] = v.y;
        tile[c][rx + 2] = v.z;
        tile[c][rx + 3] = v.w;
    }
    __syncthreads();

    unsigned int* outb = featT + (size_t)b * (HW * 128) + (size_t)s0 * 128 + (c0 >> 1);
    const int p  = t & 7;
    const int r0 = t >> 3;
    #pragma unroll
    for (int pass = 0; pass < 2; ++pass) {
        int r = pass * 32 + r0;
        unsigned int u0 = f2bf(tile[p * 8 + 0][r]) | (f2bf(tile[p * 8 + 1][r]) << 16);
        unsigned int u1 = f2bf(tile[p * 8 + 2][r]) | (f2bf(tile[p * 8 + 3][r]) << 16);
        unsigned int u2 = f2bf(tile[p * 8 + 4][r]) | (f2bf(tile[p * 8 + 5][r]) << 16);
        unsigned int u3 = f2bf(tile[p * 8 + 6][r]) | (f2bf(tile[p * 8 + 7][r]) << 16);
        *(uint4*)(outb + (size_t)r * 128 + p * 4) = make_uint4(u0, u1, u2, u3);
    }
}

// ==================================================================
// Phase 2: block = one ROI, 512 threads, uint4 loads (R5 compute,
// bit-identical). s_out staged as PACKED BF16 (26 KB vs 51 KB) and
// VGPR capped at 64 -> 4 blocks/CU = 32 waves/CU (2x R5 occupancy).
// Row stride 133 uints: conflict-free b32 LDS stores AND reads.
// ==================================================================
__global__ __launch_bounds__(512, 8) void gather_kernel(
    const unsigned short* __restrict__ featT,
    const float* __restrict__ rois,
    float* __restrict__ out)
{
    const int n = blockIdx.x;
    const int t = threadIdx.x;

    __shared__ int          s_off[NSAMP];   // pixel index with batch baked in
    __shared__ float        s_w[4][NSAMP];
    __shared__ unsigned int s_u[NBINS * 133]; // bf16-packed [bin][266 ch-slots]

    const float* rr = rois + (size_t)n * 6;

    if (t < NSAMP) {
        float cx = rr[1] * SCALE, cy = rr[2] * SCALE;
        float rw = fmaxf(rr[3] * SCALE, 0.f), rh = fmaxf(rr[4] * SCALE, 0.f);
        float theta = rr[5];
        float bin_h = rh * (1.f / OUT_H), bin_w = rw * (1.f / OUT_W);

        int sx = t & 1, sy = (t >> 1) & 1, pp = t >> 2;
        int pw = pp % OUT_W, ph = pp / OUT_W;

        float yy = bin_h * ((float)ph + ((float)sy + 0.5f) * 0.5f) - rh * 0.5f;
        float xx = bin_w * ((float)pw + ((float)sx + 0.5f) * 0.5f) - rw * 0.5f;
        float ct = cosf(theta), st = sinf(theta);
        float x = xx * ct + yy * st + cx;
        float y = yy * ct - xx * st + cy;

        float v = (y > -1.f && y < (float)FH && x > -1.f && x < (float)FW) ? 0.25f : 0.f;
        float ycl = fminf(fmaxf(y, 0.f), (float)(FH - 1));
        float xcl = fminf(fmaxf(x, 0.f), (float)(FW - 1));
        float y0f = fminf(fmaxf(floorf(ycl), 0.f), (float)(FH - 2));
        float x0f = fminf(fmaxf(floorf(xcl), 0.f), (float)(FW - 2));
        int y0 = (int)y0f, x0 = (int)x0f;
        float ly = ycl - y0f, lx = xcl - x0f;
        float hy = 1.f - ly, hx = 1.f - lx;

        s_off[t] = ((int)rr[0]) * HW + y0 * FW + x0;
        s_w[0][t] = hy * hx * v;            // (y0,x0)
        s_w[1][t] = hy * lx * v;            // (y0,x1)
        s_w[2][t] = ly * hx * v;            // (y1,x0)
        s_w[3][t] = ly * lx * v;            // (y1,x1)
    }
    __syncthreads();

    const int lane = t & 63;
    const int w    = t >> 6;                // 8 waves
    const int cl   = lane >> 1;             // channel octet: channels 8cl..8cl+7
    const int half = lane & 1;              // 0: x0 column, 1: x1 column

    for (int pp = w; pp < NBINS; pp += 8) {
        float a0=0.f,a1=0.f,a2=0.f,a3=0.f,a4=0.f,a5=0.f,a6=0.f,a7=0.f;
        #pragma unroll
        for (int k = 0; k < 4; ++k) {
            int sid = pp * 4 + k;
            size_t base = (size_t)s_off[sid] * 256 + 8 * cl + 256 * half;
            float wa = s_w[half][sid];       // row y0, this x column
            float wb = s_w[2 + half][sid];   // row y1, this x column
            uint4 va = *(const uint4*)(featT + base);
            uint4 vb = *(const uint4*)(featT + base + 256 * FW);
            a0 += wa * BFLO(va.x) + wb * BFLO(vb.x);
            a1 += wa * BFHI(va.x) + wb * BFHI(vb.x);
            a2 += wa * BFLO(va.y) + wb * BFLO(vb.y);
            a3 += wa * BFHI(va.y) + wb * BFHI(vb.y);
            a4 += wa * BFLO(va.z) + wb * BFLO(vb.z);
            a5 += wa * BFHI(va.z) + wb * BFHI(vb.z);
            a6 += wa * BFLO(va.w) + wb * BFLO(vb.w);
            a7 += wa * BFHI(va.w) + wb * BFHI(vb.w);
        }
        // combine x0/x1 columns from partner lane (lane^1)
        a0 += __shfl_xor(a0, 1); a1 += __shfl_xor(a1, 1);
        a2 += __shfl_xor(a2, 1); a3 += __shfl_xor(a3, 1);
        a4 += __shfl_xor(a4, 1); a5 += __shfl_xor(a5, 1);
        a6 += __shfl_xor(a6, 1); a7 += __shfl_xor(a7, 1);

        // lane keeps channels 4*lane .. 4*lane+3  (= 8cl + 4half + 0..3)
        float r0 = half ? a4 : a0;
        float r1 = half ? a5 : a1;
        float r2 = half ? a6 : a2;
        float r3 = half ? a7 : a3;
        // pack to bf16 pairs; b32 stores at even stride -> 2-way (free)
        s_u[pp * 133 + 2 * lane]     = f2bf(r0) | (f2bf(r1) << 16);
        s_u[pp * 133 + 2 * lane + 1] = f2bf(r2) | (f2bf(r3) << 16);
    }
    __syncthreads();

    // coalesced nontemporal writeback: out[n][c][ph][pw], 12544 floats.
    // LDS reads at stride 133 (mod 32 = 5) -> conflict-free.
    float* o = out + (size_t)n * (CCH * NBINS);
    for (int g = t; g < CCH * NBINS; g += 512) {
        int c  = g / NBINS;
        int pp = g - c * NBINS;
        unsigned int u = s_u[pp * 133 + (c >> 1)];
        float f = (c & 1) ? BFHI(u) : BFLO(u);
        __builtin_nontemporal_store(f, o + g);
    }
}

// ==================================================================
// Fallback path (ws too small): round-2 sorted clustered gather.
// ==================================================================
__global__ __launch_bounds__(1024) void sort_rois_kernel(
    const float* __restrict__ rois, int N, int* __restrict__ perm)
{
    __shared__ int s_key[1024];
    __shared__ int s_val[1024];
    const int t = threadIdx.x;

    int key = 0x7FFFFFFF, val = 0;
    if (t < N) {
        const float* r = rois + (size_t)t * 6;
        int bi = (int)r[0];
        int cyb = min(15, max(0, (int)(r[2] * SCALE * (1.f / 16.f))));
        int cxb = min(15, max(0, (int)(r[1] * SCALE * (1.f / 16.f))));
        key = (bi << 18) | (cyb << 14) | (cxb << 10) | t;
        val = t;
    }
    s_key[t] = key; s_val[t] = val;
    __syncthreads();

    for (int k = 2; k <= 1024; k <<= 1) {
        for (int j = k >> 1; j > 0; j >>= 1) {
            int ixj = t ^ j;
            if (ixj > t) {
                int a = s_key[t], bkey = s_key[ixj];
                bool up = ((t & k) == 0);
                if ((a > bkey) == up) {
                    s_key[t] = bkey; s_key[ixj] = a;
                    int av = s_val[t]; s_val[t] = s_val[ixj]; s_val[ixj] = av;
                }
            }
            __syncthreads();
        }
    }
    if (t < N) perm[t] = s_val[t];
}

__global__ __launch_bounds__(256) void rroi_align_fallback(
    const float* __restrict__ feat,
    const float* __restrict__ rois,
    const int* __restrict__ perm,
    int N, int P,
    float* __restrict__ out)
{
    const int b   = blockIdx.x;
    const int xcd = b & 7;
    const int s   = b >> 3;
    const int gy  = s / P;
    const int rl  = s - gy * P;
    const int r   = xcd * P + rl;
    if (r >= N) return;
    const int n = perm ? perm[r] : r;
    const int t = threadIdx.x;

    __shared__ int   s_off[NSAMP];
    __shared__ float s_w0[NSAMP], s_w1[NSAMP], s_w2[NSAMP], s_w3[NSAMP];
    __shared__ int   s_b;

    const float* rr = rois + (size_t)n * 6;

    if (t < NSAMP) {
        float cx = rr[1] * SCALE, cy = rr[2] * SCALE;
        float rw = fmaxf(rr[3] * SCALE, 0.f), rh = fmaxf(rr[4] * SCALE, 0.f);
        float theta = rr[5];
        float bin_h = rh * (1.f / OUT_H), bin_w = rw * (1.f / OUT_W);

        int sx = t & 1, sy = (t >> 1) & 1, pp = t >> 2;
        int pw = pp % OUT_W, ph = pp / OUT_W;

        float yy = bin_h * ((float)ph + ((float)sy + 0.5f) * 0.5f) - rh * 0.5f;
        float xx = bin_w * ((float)pw + ((float)sx + 0.5f) * 0.5f) - rw * 0.5f;
        float ct = cosf(theta), st = sinf(theta);
        float x = xx * ct + yy * st + cx;
        float y = yy * ct - xx * st + cy;

        float v = (y > -1.f && y < (float)FH && x > -1.f && x < (float)FW) ? 0.25f : 0.f;
        float ycl = fminf(fmaxf(y, 0.f), (float)(FH - 1));
        float xcl = fminf(fmaxf(x, 0.f), (float)(FW - 1));
        float y0f = fminf(fmaxf(floorf(ycl), 0.f), (float)(FH - 2));
        float x0f = fminf(fmaxf(floorf(xcl), 0.f), (float)(FW - 2));
        int y0 = (int)y0f, x0 = (int)x0f;
        float ly = ycl - y0f, lx = xcl - x0f;
        float hy = 1.f - ly, hx = 1.f - lx;

        s_off[t] = y0 * FW + x0;
        s_w0[t] = hy * hx * v;
        s_w1[t] = hy * lx * v;
        s_w2[t] = ly * hx * v;
        s_w3[t] = ly * lx * v;
        if (t == 0) s_b = (int)rr[0];
    }
    __syncthreads();

    const float* fb = feat + (size_t)s_b * CHW;

    #pragma unroll
    for (int i = 0; i < 7; ++i) {
        int flat = (gy * 7 + i) * 256 + t;
        int c  = flat / 49;
        int pp = flat - c * 49;
        const float* fc = fb + (size_t)c * HW;

        float acc = 0.f;
        #pragma unroll
        for (int k = 0; k < 4; ++k) {
            int sid = pp * 4 + k;
            const float* p = fc + s_off[sid];
            acc += s_w0[sid] * p[0]  + s_w1[sid] * p[1]
                 + s_w2[sid] * p[FW] + s_w3[sid] * p[FW + 1];
        }
        out[(size_t)n * (CCH * OUT_H * OUT_W) + flat] = acc;
    }
}

extern "C" void kernel_launch(void* const* d_in, const int* in_sizes, int n_in,
                              void* d_out, int out_size, void* d_ws, size_t ws_size,
                              hipStream_t stream)
{
    const float* feat = (const float*)d_in[0];
    const float* rois = (const float*)d_in[1];
    float* out = (float*)d_out;
    int N = in_sizes[1] / 6;
    int B = in_sizes[0] / CHW;

    const size_t needT = (size_t)B * HW * CCH * 2;   // bf16 transposed copy

    if (ws_size >= needT) {
        unsigned int* featT = (unsigned int*)d_ws;
        dim3 tg(HW / 64, CCH / 64, B);
        transpose_kernel<<<tg, 256, 0, stream>>>(feat, featT);
        gather_kernel<<<N, 512, 0, stream>>>((const unsigned short*)d_ws, rois, out);
    } else if (ws_size >= 4096 && N <= 1024) {
        int* perm = (int*)d_ws;
        sort_rois_kernel<<<1, 1024, 0, stream>>>(rois, N, perm);
        int P  = (N + 7) / 8;
        int NB = 8 * P * 7;
        rroi_align_fallback<<<NB, 256, 0, stream>>>(feat, rois, perm, N, P, out);
    } else {
        int P  = (N + 7) / 8;
        int NB = 8 * P * 7;
        rroi_align_fallback<<<NB, 256, 0, stream>>>(feat, rois, (const int*)nullptr, N, P, out);
    }
}

// Round 9
// 134.418 us; speedup vs baseline: 1.3413x; 1.3413x over previous
//
#include <hip/hip_runtime.h>

#define OUT_H 7
#define OUT_W 7
#define NBINS (OUT_H * OUT_W)           // 49
#define NSAMP (NBINS * 2 * 2)           // 196 sample points per ROI
#define CCH 256
#define FH 256
#define FW 256
#define HW (FH * FW)
#define CHW (CCH * HW)
#define SCALE 0.25f

typedef float v4f __attribute__((ext_vector_type(4)));

// ---------- bf16 helpers (RNE) ----------
__device__ __forceinline__ unsigned int f2bf(float f) {
    unsigned int u = __float_as_uint(f);
    u += 0x7FFFu + ((u >> 16) & 1u);
    return u >> 16;
}
#define BFLO(u) __uint_as_float((u) << 16)
#define BFHI(u) __uint_as_float((u) & 0xFFFF0000u)

// ==================================================================
// Phase 1: transpose BCHW fp32 -> BHWC bf16 (featT in d_ws).
// (unchanged from round 7 — ~92% of its HBM floor)
// ==================================================================
__global__ __launch_bounds__(256) void transpose_kernel(
    const float* __restrict__ feat, unsigned int* __restrict__ featT)
{
    __shared__ float tile[64][65];
    const int t  = threadIdx.x;
    const int s0 = blockIdx.x * 64;
    const int c0 = blockIdx.y * 64;
    const int b  = blockIdx.z;

    const float* inb = feat + (size_t)b * CHW + (size_t)c0 * HW + s0;

    const int rx = (t & 15) * 4;
    const int rc = t >> 4;
    #pragma unroll
    for (int pass = 0; pass < 4; ++pass) {
        int c = pass * 16 + rc;
        float4 v = *(const float4*)(inb + (size_t)c * HW + rx);
        tile[c][rx]     = v.x;
        tile[c][rx + 1] = v.y;
        tile[c][rx + 2] = v.z;
        tile[c][rx + 3] = v.w;
    }
    __syncthreads();

    unsigned int* outb = featT + (size_t)b * (HW * 128) + (size_t)s0 * 128 + (c0 >> 1);
    const int p  = t & 7;
    const int r0 = t >> 3;
    #pragma unroll
    for (int pass = 0; pass < 2; ++pass) {
        int r = pass * 32 + r0;
        unsigned int u0 = f2bf(tile[p * 8 + 0][r]) | (f2bf(tile[p * 8 + 1][r]) << 16);
        unsigned int u1 = f2bf(tile[p * 8 + 2][r]) | (f2bf(tile[p * 8 + 3][r]) << 16);
        unsigned int u2 = f2bf(tile[p * 8 + 4][r]) | (f2bf(tile[p * 8 + 5][r]) << 16);
        unsigned int u3 = f2bf(tile[p * 8 + 6][r]) | (f2bf(tile[p * 8 + 7][r]) << 16);
        *(uint4*)(outb + (size_t)r * 128 + p * 4) = make_uint4(u0, u1, u2, u3);
    }
}

// ==================================================================
// Phase 2: block = one ROI, 512 threads, uint4 loads (R5/R7 lane map).
// bf16 LDS staging (29.3 KB -> LDS allows 5 blocks/CU).
// __launch_bounds__(512,6): VGPR <= 85 -> 24 waves/CU (1.5x R7).
// k-loop split into TWO sequential 2-sample phases: only 4 uint4
// in flight -> live set ~55-60 VGPR, no spills (the R8 failure mode).
// ==================================================================
__global__ __launch_bounds__(512, 6) void gather_kernel(
    const unsigned short* __restrict__ featT,
    const float* __restrict__ rois,
    float* __restrict__ out)
{
    const int n = blockIdx.x;
    const int t = threadIdx.x;

    __shared__ int          s_off[NSAMP];     // pixel index with batch baked in
    __shared__ float        s_w[4][NSAMP];
    __shared__ unsigned int s_u[NBINS * 133]; // bf16-packed [bin][266 ch-slots]

    const float* rr = rois + (size_t)n * 6;

    if (t < NSAMP) {
        float cx = rr[1] * SCALE, cy = rr[2] * SCALE;
        float rw = fmaxf(rr[3] * SCALE, 0.f), rh = fmaxf(rr[4] * SCALE, 0.f);
        float theta = rr[5];
        float bin_h = rh * (1.f / OUT_H), bin_w = rw * (1.f / OUT_W);

        int sx = t & 1, sy = (t >> 1) & 1, pp = t >> 2;
        int pw = pp % OUT_W, ph = pp / OUT_W;

        float yy = bin_h * ((float)ph + ((float)sy + 0.5f) * 0.5f) - rh * 0.5f;
        float xx = bin_w * ((float)pw + ((float)sx + 0.5f) * 0.5f) - rw * 0.5f;
        float ct = cosf(theta), st = sinf(theta);
        float x = xx * ct + yy * st + cx;
        float y = yy * ct - xx * st + cy;

        float v = (y > -1.f && y < (float)FH && x > -1.f && x < (float)FW) ? 0.25f : 0.f;
        float ycl = fminf(fmaxf(y, 0.f), (float)(FH - 1));
        float xcl = fminf(fmaxf(x, 0.f), (float)(FW - 1));
        float y0f = fminf(fmaxf(floorf(ycl), 0.f), (float)(FH - 2));
        float x0f = fminf(fmaxf(floorf(xcl), 0.f), (float)(FW - 2));
        int y0 = (int)y0f, x0 = (int)x0f;
        float ly = ycl - y0f, lx = xcl - x0f;
        float hy = 1.f - ly, hx = 1.f - lx;

        s_off[t] = ((int)rr[0]) * HW + y0 * FW + x0;
        s_w[0][t] = hy * hx * v;            // (y0,x0)
        s_w[1][t] = hy * lx * v;            // (y0,x1)
        s_w[2][t] = ly * hx * v;            // (y1,x0)
        s_w[3][t] = ly * lx * v;            // (y1,x1)
    }
    __syncthreads();

    const int lane = t & 63;
    const int w    = t >> 6;                // 8 waves
    const int cl   = lane >> 1;             // channel octet: channels 8cl..8cl+7
    const int half = lane & 1;              // 0: x0 column, 1: x1 column

    for (int pp = w; pp < NBINS; pp += 8) {
        float a0=0.f,a1=0.f,a2=0.f,a3=0.f,a4=0.f,a5=0.f,a6=0.f,a7=0.f;

        // ---- phase A: samples k=0,1 (4 uint4 in flight) ----
        {
            int sid0 = pp * 4 + 0, sid1 = pp * 4 + 1;
            size_t b0 = (size_t)s_off[sid0] * 256 + 8 * cl + 256 * half;
            size_t b1 = (size_t)s_off[sid1] * 256 + 8 * cl + 256 * half;
            uint4 va0 = *(const uint4*)(featT + b0);
            uint4 vb0 = *(const uint4*)(featT + b0 + 256 * FW);
            uint4 va1 = *(const uint4*)(featT + b1);
            uint4 vb1 = *(const uint4*)(featT + b1 + 256 * FW);
            float wa0 = s_w[half][sid0], wb0 = s_w[2 + half][sid0];
            float wa1 = s_w[half][sid1], wb1 = s_w[2 + half][sid1];
            a0 += wa0 * BFLO(va0.x) + wb0 * BFLO(vb0.x) + wa1 * BFLO(va1.x) + wb1 * BFLO(vb1.x);
            a1 += wa0 * BFHI(va0.x) + wb0 * BFHI(vb0.x) + wa1 * BFHI(va1.x) + wb1 * BFHI(vb1.x);
            a2 += wa0 * BFLO(va0.y) + wb0 * BFLO(vb0.y) + wa1 * BFLO(va1.y) + wb1 * BFLO(vb1.y);
            a3 += wa0 * BFHI(va0.y) + wb0 * BFHI(vb0.y) + wa1 * BFHI(va1.y) + wb1 * BFHI(vb1.y);
            a4 += wa0 * BFLO(va0.z) + wb0 * BFLO(vb0.z) + wa1 * BFLO(va1.z) + wb1 * BFLO(vb1.z);
            a5 += wa0 * BFHI(va0.z) + wb0 * BFHI(vb0.z) + wa1 * BFHI(va1.z) + wb1 * BFHI(vb1.z);
            a6 += wa0 * BFLO(va0.w) + wb0 * BFLO(vb0.w) + wa1 * BFLO(va1.w) + wb1 * BFLO(vb1.w);
            a7 += wa0 * BFHI(va0.w) + wb0 * BFHI(vb0.w) + wa1 * BFHI(va1.w) + wb1 * BFHI(vb1.w);
        }
        // ---- phase B: samples k=2,3 ----
        {
            int sid0 = pp * 4 + 2, sid1 = pp * 4 + 3;
            size_t b0 = (size_t)s_off[sid0] * 256 + 8 * cl + 256 * half;
            size_t b1 = (size_t)s_off[sid1] * 256 + 8 * cl + 256 * half;
            uint4 va0 = *(const uint4*)(featT + b0);
            uint4 vb0 = *(const uint4*)(featT + b0 + 256 * FW);
            uint4 va1 = *(const uint4*)(featT + b1);
            uint4 vb1 = *(const uint4*)(featT + b1 + 256 * FW);
            float wa0 = s_w[half][sid0], wb0 = s_w[2 + half][sid0];
            float wa1 = s_w[half][sid1], wb1 = s_w[2 + half][sid1];
            a0 += wa0 * BFLO(va0.x) + wb0 * BFLO(vb0.x) + wa1 * BFLO(va1.x) + wb1 * BFLO(vb1.x);
            a1 += wa0 * BFHI(va0.x) + wb0 * BFHI(vb0.x) + wa1 * BFHI(va1.x) + wb1 * BFHI(vb1.x);
            a2 += wa0 * BFLO(va0.y) + wb0 * BFLO(vb0.y) + wa1 * BFLO(va1.y) + wb1 * BFLO(vb1.y);
            a3 += wa0 * BFHI(va0.y) + wb0 * BFHI(vb0.y) + wa1 * BFHI(va1.y) + wb1 * BFHI(vb1.y);
            a4 += wa0 * BFLO(va0.z) + wb0 * BFLO(vb0.z) + wa1 * BFLO(va1.z) + wb1 * BFLO(vb1.z);
            a5 += wa0 * BFHI(va0.z) + wb0 * BFHI(vb0.z) + wa1 * BFHI(va1.z) + wb1 * BFHI(vb1.z);
            a6 += wa0 * BFLO(va0.w) + wb0 * BFLO(vb0.w) + wa1 * BFLO(va1.w) + wb1 * BFLO(vb1.w);
            a7 += wa0 * BFHI(va0.w) + wb0 * BFHI(vb0.w) + wa1 * BFHI(va1.w) + wb1 * BFHI(vb1.w);
        }

        // combine x0/x1 columns from partner lane (lane^1)
        a0 += __shfl_xor(a0, 1); a1 += __shfl_xor(a1, 1);
        a2 += __shfl_xor(a2, 1); a3 += __shfl_xor(a3, 1);
        a4 += __shfl_xor(a4, 1); a5 += __shfl_xor(a5, 1);
        a6 += __shfl_xor(a6, 1); a7 += __shfl_xor(a7, 1);

        // lane keeps channels 4*lane .. 4*lane+3  (= 8cl + 4half + 0..3)
        float r0 = half ? a4 : a0;
        float r1 = half ? a5 : a1;
        float r2 = half ? a6 : a2;
        float r3 = half ? a7 : a3;
        // b32 stores stride 2 -> 2-way bank alias (free)
        s_u[pp * 133 + 2 * lane]     = f2bf(r0) | (f2bf(r1) << 16);
        s_u[pp * 133 + 2 * lane + 1] = f2bf(r2) | (f2bf(r3) << 16);
    }
    __syncthreads();

    // coalesced nontemporal writeback: out[n][c][ph][pw], 12544 floats.
    // LDS reads at row stride 133 (mod 32 = 5, odd) -> conflict-free.
    float* o = out + (size_t)n * (CCH * NBINS);
    for (int g = t; g < CCH * NBINS; g += 512) {
        int c  = g / NBINS;
        int pp = g - c * NBINS;
        unsigned int u = s_u[pp * 133 + (c >> 1)];
        float f = (c & 1) ? BFHI(u) : BFLO(u);
        __builtin_nontemporal_store(f, o + g);
    }
}

// ==================================================================
// Fallback path (ws too small): round-2 sorted clustered gather.
// ==================================================================
__global__ __launch_bounds__(1024) void sort_rois_kernel(
    const float* __restrict__ rois, int N, int* __restrict__ perm)
{
    __shared__ int s_key[1024];
    __shared__ int s_val[1024];
    const int t = threadIdx.x;

    int key = 0x7FFFFFFF, val = 0;
    if (t < N) {
        const float* r = rois + (size_t)t * 6;
        int bi = (int)r[0];
        int cyb = min(15, max(0, (int)(r[2] * SCALE * (1.f / 16.f))));
        int cxb = min(15, max(0, (int)(r[1] * SCALE * (1.f / 16.f))));
        key = (bi << 18) | (cyb << 14) | (cxb << 10) | t;
        val = t;
    }
    s_key[t] = key; s_val[t] = val;
    __syncthreads();

    for (int k = 2; k <= 1024; k <<= 1) {
        for (int j = k >> 1; j > 0; j >>= 1) {
            int ixj = t ^ j;
            if (ixj > t) {
                int a = s_key[t], bkey = s_key[ixj];
                bool up = ((t & k) == 0);
                if ((a > bkey) == up) {
                    s_key[t] = bkey; s_key[ixj] = a;
                    int av = s_val[t]; s_val[t] = s_val[ixj]; s_val[ixj] = av;
                }
            }
            __syncthreads();
        }
    }
    if (t < N) perm[t] = s_val[t];
}

__global__ __launch_bounds__(256) void rroi_align_fallback(
    const float* __restrict__ feat,
    const float* __restrict__ rois,
    const int* __restrict__ perm,
    int N, int P,
    float* __restrict__ out)
{
    const int b   = blockIdx.x;
    const int xcd = b & 7;
    const int s   = b >> 3;
    const int gy  = s / P;
    const int rl  = s - gy * P;
    const int r   = xcd * P + rl;
    if (r >= N) return;
    const int n = perm ? perm[r] : r;
    const int t = threadIdx.x;

    __shared__ int   s_off[NSAMP];
    __shared__ float s_w0[NSAMP], s_w1[NSAMP], s_w2[NSAMP], s_w3[NSAMP];
    __shared__ int   s_b;

    const float* rr = rois + (size_t)n * 6;

    if (t < NSAMP) {
        float cx = rr[1] * SCALE, cy = rr[2] * SCALE;
        float rw = fmaxf(rr[3] * SCALE, 0.f), rh = fmaxf(rr[4] * SCALE, 0.f);
        float theta = rr[5];
        float bin_h = rh * (1.f / OUT_H), bin_w = rw * (1.f / OUT_W);

        int sx = t & 1, sy = (t >> 1) & 1, pp = t >> 2;
        int pw = pp % OUT_W, ph = pp / OUT_W;

        float yy = bin_h * ((float)ph + ((float)sy + 0.5f) * 0.5f) - rh * 0.5f;
        float xx = bin_w * ((float)pw + ((float)sx + 0.5f) * 0.5f) - rw * 0.5f;
        float ct = cosf(theta), st = sinf(theta);
        float x = xx * ct + yy * st + cx;
        float y = yy * ct - xx * st + cy;

        float v = (y > -1.f && y < (float)FH && x > -1.f && x < (float)FW) ? 0.25f : 0.f;
        float ycl = fminf(fmaxf(y, 0.f), (float)(FH - 1));
        float xcl = fminf(fmaxf(x, 0.f), (float)(FW - 1));
        float y0f = fminf(fmaxf(floorf(ycl), 0.f), (float)(FH - 2));
        float x0f = fminf(fmaxf(floorf(xcl), 0.f), (float)(FW - 2));
        int y0 = (int)y0f, x0 = (int)x0f;
        float ly = ycl - y0f, lx = xcl - x0f;
        float hy = 1.f - ly, hx = 1.f - lx;

        s_off[t] = y0 * FW + x0;
        s_w0[t] = hy * hx * v;
        s_w1[t] = hy * lx * v;
        s_w2[t] = ly * hx * v;
        s_w3[t] = ly * lx * v;
        if (t == 0) s_b = (int)rr[0];
    }
    __syncthreads();

    const float* fb = feat + (size_t)s_b * CHW;

    #pragma unroll
    for (int i = 0; i < 7; ++i) {
        int flat = (gy * 7 + i) * 256 + t;
        int c  = flat / 49;
        int pp = flat - c * 49;
        const float* fc = fb + (size_t)c * HW;

        float acc = 0.f;
        #pragma unroll
        for (int k = 0; k < 4; ++k) {
            int sid = pp * 4 + k;
            const float* p = fc + s_off[sid];
            acc += s_w0[sid] * p[0]  + s_w1[sid] * p[1]
                 + s_w2[sid] * p[FW] + s_w3[sid] * p[FW + 1];
        }
        out[(size_t)n * (CCH * OUT_H * OUT_W) + flat] = acc;
    }
}

extern "C" void kernel_launch(void* const* d_in, const int* in_sizes, int n_in,
                              void* d_out, int out_size, void* d_ws, size_t ws_size,
                              hipStream_t stream)
{
    const float* feat = (const float*)d_in[0];
    const float* rois = (const float*)d_in[1];
    float* out = (float*)d_out;
    int N = in_sizes[1] / 6;
    int B = in_sizes[0] / CHW;

    const size_t needT = (size_t)B * HW * CCH * 2;   // bf16 transposed copy

    if (ws_size >= needT) {
        unsigned int* featT = (unsigned int*)d_ws;
        dim3 tg(HW / 64, CCH / 64, B);
        transpose_kernel<<<tg, 256, 0, stream>>>(feat, featT);
        gather_kernel<<<N, 512, 0, stream>>>((const unsigned short*)d_ws, rois, out);
    } else if (ws_size >= 4096 && N <= 1024) {
        int* perm = (int*)d_ws;
        sort_rois_kernel<<<1, 1024, 0, stream>>>(rois, N, perm);
        int P  = (N + 7) / 8;
        int NB = 8 * P * 7;
        rroi_align_fallback<<<NB, 256, 0, stream>>>(feat, rois, perm, N, P, out);
    } else {
        int P  = (N + 7) / 8;
        int NB = 8 * P * 7;
        rroi_align_fallback<<<NB, 256, 0, stream>>>(feat, rois, (const int*)nullptr, N, P, out);
    }
}

// Round 10
// 116.095 us; speedup vs baseline: 1.5530x; 1.1578x over previous
//
#include <hip/hip_runtime.h>

#define OUT_H 7
#define OUT_W 7
#define NBINS (OUT_H * OUT_W)           // 49
#define NSAMP (NBINS * 2 * 2)           // 196 sample points per ROI
#define CCH 256
#define FH 256
#define FW 256
#define HW (FH * FW)
#define CHW (CCH * HW)
#define SCALE 0.25f

typedef float v4f __attribute__((ext_vector_type(4)));

// ---------- bf16 helpers (RNE) ----------
__device__ __forceinline__ unsigned int f2bf(float f) {
    unsigned int u = __float_as_uint(f);
    u += 0x7FFFu + ((u >> 16) & 1u);
    return u >> 16;
}
#define BFLO(u) __uint_as_float((u) << 16)
#define BFHI(u) __uint_as_float((u) & 0xFFFF0000u)

// ==================================================================
// Phase 1: transpose BCHW fp32 -> BHWC bf16 (featT in d_ws).
// Tile 64 channels x 64 spatial. Nontemporal float4 reads (zero-reuse
// stream, keep it out of L3), uint4 bf16-packed writes (plain stores:
// featT SHOULD allocate in L3 -- gather reads it ~3x).
// ==================================================================
__global__ __launch_bounds__(256) void transpose_kernel(
    const float* __restrict__ feat, unsigned int* __restrict__ featT)
{
    __shared__ float tile[64][65];
    const int t  = threadIdx.x;
    const int s0 = blockIdx.x * 64;
    const int c0 = blockIdx.y * 64;
    const int b  = blockIdx.z;

    const float* inb = feat + (size_t)b * CHW + (size_t)c0 * HW + s0;

    const int rx = (t & 15) * 4;
    const int rc = t >> 4;
    #pragma unroll
    for (int pass = 0; pass < 4; ++pass) {
        int c = pass * 16 + rc;
        v4f v = __builtin_nontemporal_load((const v4f*)(inb + (size_t)c * HW + rx));
        tile[c][rx]     = v.x;
        tile[c][rx + 1] = v.y;
        tile[c][rx + 2] = v.z;
        tile[c][rx + 3] = v.w;
    }
    __syncthreads();

    unsigned int* outb = featT + (size_t)b * (HW * 128) + (size_t)s0 * 128 + (c0 >> 1);
    const int p  = t & 7;
    const int r0 = t >> 3;
    #pragma unroll
    for (int pass = 0; pass < 2; ++pass) {
        int r = pass * 32 + r0;
        unsigned int u0 = f2bf(tile[p * 8 + 0][r]) | (f2bf(tile[p * 8 + 1][r]) << 16);
        unsigned int u1 = f2bf(tile[p * 8 + 2][r]) | (f2bf(tile[p * 8 + 3][r]) << 16);
        unsigned int u2 = f2bf(tile[p * 8 + 4][r]) | (f2bf(tile[p * 8 + 5][r]) << 16);
        unsigned int u3 = f2bf(tile[p * 8 + 6][r]) | (f2bf(tile[p * 8 + 7][r]) << 16);
        *(uint4*)(outb + (size_t)r * 128 + p * 4) = make_uint4(u0, u1, u2, u3);
    }
}

// ==================================================================
// Phase 2 (R7, proven 125us): block = one ROI, 512 threads, uint4
// loads (8 in flight per lane-iter). fp32 LDS staging; single
// fully-coalesced NONTEMPORAL writeback.
// ==================================================================
__global__ __launch_bounds__(512) void gather_kernel(
    const unsigned short* __restrict__ featT,
    const float* __restrict__ rois,
    float* __restrict__ out)
{
    const int n = blockIdx.x;
    const int t = threadIdx.x;

    __shared__ int   s_off[NSAMP];          // pixel index with batch baked in
    __shared__ float s_w[4][NSAMP];
    __shared__ float s_out[NBINS][260];     // [bin][channel], stride 260 (16B-aligned)

    const float* rr = rois + (size_t)n * 6;

    if (t < NSAMP) {
        float cx = rr[1] * SCALE, cy = rr[2] * SCALE;
        float rw = fmaxf(rr[3] * SCALE, 0.f), rh = fmaxf(rr[4] * SCALE, 0.f);
        float theta = rr[5];
        float bin_h = rh * (1.f / OUT_H), bin_w = rw * (1.f / OUT_W);

        int sx = t & 1, sy = (t >> 1) & 1, pp = t >> 2;
        int pw = pp % OUT_W, ph = pp / OUT_W;

        float yy = bin_h * ((float)ph + ((float)sy + 0.5f) * 0.5f) - rh * 0.5f;
        float xx = bin_w * ((float)pw + ((float)sx + 0.5f) * 0.5f) - rw * 0.5f;
        float ct = cosf(theta), st = sinf(theta);
        float x = xx * ct + yy * st + cx;
        float y = yy * ct - xx * st + cy;

        float v = (y > -1.f && y < (float)FH && x > -1.f && x < (float)FW) ? 0.25f : 0.f;
        float ycl = fminf(fmaxf(y, 0.f), (float)(FH - 1));
        float xcl = fminf(fmaxf(x, 0.f), (float)(FW - 1));
        float y0f = fminf(fmaxf(floorf(ycl), 0.f), (float)(FH - 2));
        float x0f = fminf(fmaxf(floorf(xcl), 0.f), (float)(FW - 2));
        int y0 = (int)y0f, x0 = (int)x0f;
        float ly = ycl - y0f, lx = xcl - x0f;
        float hy = 1.f - ly, hx = 1.f - lx;

        s_off[t] = ((int)rr[0]) * HW + y0 * FW + x0;
        s_w[0][t] = hy * hx * v;            // (y0,x0)
        s_w[1][t] = hy * lx * v;            // (y0,x1)
        s_w[2][t] = ly * hx * v;            // (y1,x0)
        s_w[3][t] = ly * lx * v;            // (y1,x1)
    }
    __syncthreads();

    const int lane = t & 63;
    const int w    = t >> 6;                // 8 waves
    const int cl   = lane >> 1;             // channel octet: channels 8cl..8cl+7
    const int half = lane & 1;              // 0: x0 column, 1: x1 column

    for (int pp = w; pp < NBINS; pp += 8) {
        float a0=0.f,a1=0.f,a2=0.f,a3=0.f,a4=0.f,a5=0.f,a6=0.f,a7=0.f;
        #pragma unroll
        for (int k = 0; k < 4; ++k) {
            int sid = pp * 4 + k;
            size_t base = (size_t)s_off[sid] * 256 + 8 * cl + 256 * half;
            float wa = s_w[half][sid];       // row y0, this x column
            float wb = s_w[2 + half][sid];   // row y1, this x column
            uint4 va = *(const uint4*)(featT + base);
            uint4 vb = *(const uint4*)(featT + base + 256 * FW);
            a0 += wa * BFLO(va.x) + wb * BFLO(vb.x);
            a1 += wa * BFHI(va.x) + wb * BFHI(vb.x);
            a2 += wa * BFLO(va.y) + wb * BFLO(vb.y);
            a3 += wa * BFHI(va.y) + wb * BFHI(vb.y);
            a4 += wa * BFLO(va.z) + wb * BFLO(vb.z);
            a5 += wa * BFHI(va.z) + wb * BFHI(vb.z);
            a6 += wa * BFLO(va.w) + wb * BFLO(vb.w);
            a7 += wa * BFHI(va.w) + wb * BFHI(vb.w);
        }
        // combine x0/x1 columns from partner lane (lane^1)
        a0 += __shfl_xor(a0, 1); a1 += __shfl_xor(a1, 1);
        a2 += __shfl_xor(a2, 1); a3 += __shfl_xor(a3, 1);
        a4 += __shfl_xor(a4, 1); a5 += __shfl_xor(a5, 1);
        a6 += __shfl_xor(a6, 1); a7 += __shfl_xor(a7, 1);

        // lane keeps channels 4*lane .. 4*lane+3  (= 8cl + 4half + 0..3)
        float4 r = half ? make_float4(a4, a5, a6, a7)
                        : make_float4(a0, a1, a2, a3);
        *(float4*)&s_out[pp][4 * lane] = r;   // contiguous 1KB per wave, conflict-free
    }
    __syncthreads();

    // fully coalesced writeback: out[n][c][ph][pw], 12544 consecutive floats.
    // Nontemporal: write-once output must not evict featT from L3.
    float* o = out + (size_t)n * (CCH * NBINS);
    for (int g = t; g < CCH * NBINS; g += 512) {
        int c  = g / NBINS;
        int pp = g - c * NBINS;
        __builtin_nontemporal_store(s_out[pp][c], o + g);
    }
}

// ==================================================================
// Fallback path (ws too small): round-2 sorted clustered gather.
// ==================================================================
__global__ __launch_bounds__(1024) void sort_rois_kernel(
    const float* __restrict__ rois, int N, int* __restrict__ perm)
{
    __shared__ int s_key[1024];
    __shared__ int s_val[1024];
    const int t = threadIdx.x;

    int key = 0x7FFFFFFF, val = 0;
    if (t < N) {
        const float* r = rois + (size_t)t * 6;
        int bi = (int)r[0];
        int cyb = min(15, max(0, (int)(r[2] * SCALE * (1.f / 16.f))));
        int cxb = min(15, max(0, (int)(r[1] * SCALE * (1.f / 16.f))));
        key = (bi << 18) | (cyb << 14) | (cxb << 10) | t;
        val = t;
    }
    s_key[t] = key; s_val[t] = val;
    __syncthreads();

    for (int k = 2; k <= 1024; k <<= 1) {
        for (int j = k >> 1; j > 0; j >>= 1) {
            int ixj = t ^ j;
            if (ixj > t) {
                int a = s_key[t], bkey = s_key[ixj];
                bool up = ((t & k) == 0);
                if ((a > bkey) == up) {
                    s_key[t] = bkey; s_key[ixj] = a;
                    int av = s_val[t]; s_val[t] = s_val[ixj]; s_val[ixj] = av;
                }
            }
            __syncthreads();
        }
    }
    if (t < N) perm[t] = s_val[t];
}

__global__ __launch_bounds__(256) void rroi_align_fallback(
    const float* __restrict__ feat,
    const float* __restrict__ rois,
    const int* __restrict__ perm,
    int N, int P,
    float* __restrict__ out)
{
    const int b   = blockIdx.x;
    const int xcd = b & 7;
    const int s   = b >> 3;
    const int gy  = s / P;
    const int rl  = s - gy * P;
    const int r   = xcd * P + rl;
    if (r >= N) return;
    const int n = perm ? perm[r] : r;
    const int t = threadIdx.x;

    __shared__ int   s_off[NSAMP];
    __shared__ float s_w0[NSAMP], s_w1[NSAMP], s_w2[NSAMP], s_w3[NSAMP];
    __shared__ int   s_b;

    const float* rr = rois + (size_t)n * 6;

    if (t < NSAMP) {
        float cx = rr[1] * SCALE, cy = rr[2] * SCALE;
        float rw = fmaxf(rr[3] * SCALE, 0.f), rh = fmaxf(rr[4] * SCALE, 0.f);
        float theta = rr[5];
        float bin_h = rh * (1.f / OUT_H), bin_w = rw * (1.f / OUT_W);

        int sx = t & 1, sy = (t >> 1) & 1, pp = t >> 2;
        int pw = pp % OUT_W, ph = pp / OUT_W;

        float yy = bin_h * ((float)ph + ((float)sy + 0.5f) * 0.5f) - rh * 0.5f;
        float xx = bin_w * ((float)pw + ((float)sx + 0.5f) * 0.5f) - rw * 0.5f;
        float ct = cosf(theta), st = sinf(theta);
        float x = xx * ct + yy * st + cx;
        float y = yy * ct - xx * st + cy;

        float v = (y > -1.f && y < (float)FH && x > -1.f && x < (float)FW) ? 0.25f : 0.f;
        float ycl = fminf(fmaxf(y, 0.f), (float)(FH - 1));
        float xcl = fminf(fmaxf(x, 0.f), (float)(FW - 1));
        float y0f = fminf(fmaxf(floorf(ycl), 0.f), (float)(FH - 2));
        float x0f = fminf(fmaxf(floorf(xcl), 0.f), (float)(FW - 2));
        int y0 = (int)y0f, x0 = (int)x0f;
        float ly = ycl - y0f, lx = xcl - x0f;
        float hy = 1.f - ly, hx = 1.f - lx;

        s_off[t] = y0 * FW + x0;
        s_w0[t] = hy * hx * v;
        s_w1[t] = hy * lx * v;
        s_w2[t] = ly * hx * v;
        s_w3[t] = ly * lx * v;
        if (t == 0) s_b = (int)rr[0];
    }
    __syncthreads();

    const float* fb = feat + (size_t)s_b * CHW;

    #pragma unroll
    for (int i = 0; i < 7; ++i) {
        int flat = (gy * 7 + i) * 256 + t;
        int c  = flat / 49;
        int pp = flat - c * 49;
        const float* fc = fb + (size_t)c * HW;

        float acc = 0.f;
        #pragma unroll
        for (int k = 0; k < 4; ++k) {
            int sid = pp * 4 + k;
            const float* p = fc + s_off[sid];
            acc += s_w0[sid] * p[0]  + s_w1[sid] * p[1]
                 + s_w2[sid] * p[FW] + s_w3[sid] * p[FW + 1];
        }
        out[(size_t)n * (CCH * OUT_H * OUT_W) + flat] = acc;
    }
}

extern "C" void kernel_launch(void* const* d_in, const int* in_sizes, int n_in,
                              void* d_out, int out_size, void* d_ws, size_t ws_size,
                              hipStream_t stream)
{
    const float* feat = (const float*)d_in[0];
    const float* rois = (const float*)d_in[1];
    float* out = (float*)d_out;
    int N = in_sizes[1] / 6;
    int B = in_sizes[0] / CHW;

    const size_t needT = (size_t)B * HW * CCH * 2;   // bf16 transposed copy

    if (ws_size >= needT) {
        unsigned int* featT = (unsigned int*)d_ws;
        dim3 tg(HW / 64, CCH / 64, B);
        transpose_kernel<<<tg, 256, 0, stream>>>(feat, featT);
        gather_kernel<<<N, 512, 0, stream>>>((const unsigned short*)d_ws, rois, out);
    } else if (ws_size >= 4096 && N <= 1024) {
        int* perm = (int*)d_ws;
        sort_rois_kernel<<<1, 1024, 0, stream>>>(rois, N, perm);
        int P  = (N + 7) / 8;
        int NB = 8 * P * 7;
        rroi_align_fallback<<<NB, 256, 0, stream>>>(feat, rois, perm, N, P, out);
    } else {
        int P  = (N + 7) / 8;
        int NB = 8 * P * 7;
        rroi_align_fallback<<<NB, 256, 0, stream>>>(feat, rois, (const int*)nullptr, N, P, out);
    }
}